// Round 3
// baseline (32642.981 us; speedup 1.0000x reference)
//
#include <hip/hip_runtime.h>
#include <math.h>

#define T_SEQ 2048
#define HID   64
#define GATES 256
#define CHUNK 32
#define NCHUNK (T_SEQ / CHUNK)   // 64

__device__ __forceinline__ float sigmoid_(float x) {
    return 1.0f / (1.0f + __expf(-x));
}
__device__ __forceinline__ float tanh_(float x) {
    float e = __expf(2.0f * x);
    return 1.0f - 2.0f / (e + 1.0f);
}

// One LSTM layer over the whole sequence.
// grid = 256 blocks (1 per sample), block = 320 threads (5 waves):
//   wave 0   : the ENTIRE recurrence for this sample, barrier-free.
//              lane j owns hidden unit j (gate rows j, 64+j, 128+j, 192+j).
//              i,f weights in VGPRs; g,o weights read from LDS each step.
//   waves 1-4: input GEMM for chunk ci+1 (xg = in @ W_ih^T + b), double-buffered,
//              input rows staged 2 chunks ahead. One barrier per CHUNK steps.
// in/out may alias (in-place for layers >= 1): reads run >= 1 chunk ahead of
// writes, disjoint ranges every iteration.
template <int IN_DIM>
__global__ __launch_bounds__(320, 2)
void lstm_layer_kernel(const float* in,
                       const float* __restrict__ W_ih,   // [GATES, IN_DIM]
                       const float* __restrict__ W_hh,   // [GATES, HID]
                       const float* __restrict__ b_ih,   // [GATES]
                       const float* __restrict__ b_hh,   // [GATES]
                       float* out)
{
    __shared__ float s_xg[2][CHUNK][GATES];        // 64 KB  xg double buffer
    __shared__ float s_in[2][CHUNK][HID];          // 16 KB  staged input rows
    __shared__ float s_wgo[2][HID / 4][HID][4];    // 32 KB  [gsel][k4][lane][kk]
    __shared__ float s_hout[CHUNK][HID];           //  8 KB  chunk h output
    __shared__ float s_hvec[HID];                  // 256 B  current h (broadcast)

    const int tid  = threadIdx.x;
    const int wave = tid >> 6;       // 0..4
    const int lane = tid & 63;
    const int s    = blockIdx.x;

    const float* in_s  = in  + (size_t)s * T_SEQ * IN_DIM;
    float*       out_s = out + (size_t)s * T_SEQ * HID;

    // ---- zero s_in (padding cols for IN_DIM<64 stay 0 forever) + h0
    for (int i = tid; i < 2 * CHUNK * HID; i += 320) ((float*)s_in)[i] = 0.0f;
    if (tid < HID) s_hvec[tid] = 0.0f;
    __syncthreads();                                   // B1

    // ---- per-wave setup ----
    float wi[HID], wf[HID];          // wave0: i,f gate rows (VGPR)
    float wih[HID];                  // waves 1-4: W_ih row for gate gr
    float bias = 0.0f;
    float c = 0.0f, h = 0.0f;

    if (wave == 0) {
        // i,f rows into registers
#pragma unroll
        for (int k4 = 0; k4 < HID / 4; ++k4) {
            float4 a = *reinterpret_cast<const float4*>(&W_hh[(size_t)lane * HID + k4 * 4]);
            float4 b = *reinterpret_cast<const float4*>(&W_hh[(size_t)(64 + lane) * HID + k4 * 4]);
            wi[k4 * 4 + 0] = a.x; wi[k4 * 4 + 1] = a.y; wi[k4 * 4 + 2] = a.z; wi[k4 * 4 + 3] = a.w;
            wf[k4 * 4 + 0] = b.x; wf[k4 * 4 + 1] = b.y; wf[k4 * 4 + 2] = b.z; wf[k4 * 4 + 3] = b.w;
        }
        // g,o rows into LDS, layout [gsel][k4][lane][0..3] so the per-step read
        // is a conflict-free ds_read_b128 at lane*16 within each 1KB stripe
#pragma unroll
        for (int gsel = 0; gsel < 2; ++gsel)
            for (int k4 = 0; k4 < HID / 4; ++k4) {
                float4 w = *reinterpret_cast<const float4*>(
                    &W_hh[(size_t)(128 + 64 * gsel + lane) * HID + k4 * 4]);
                *reinterpret_cast<float4*>(&s_wgo[gsel][k4][lane][0]) = w;
            }
    } else {
        const int gr = (wave - 1) * 64 + lane;   // gate row 0..255
#pragma unroll
        for (int k = 0; k < HID; ++k)
            wih[k] = (k < IN_DIM) ? W_ih[(size_t)gr * IN_DIM + k] : 0.0f;
        bias = b_ih[gr] + b_hh[gr];
    }

    // ---- GEMM-side helpers (lambdas keep barrier structure uniform) ----
    const int gt = tid - 64;  // 0..255 for waves 1-4

    auto stage = [&](int b, int cc) {
        if (IN_DIM == 64) {
            const float4* src = reinterpret_cast<const float4*>(in_s + (size_t)cc * CHUNK * 64);
            float4* dst = reinterpret_cast<float4*>(&s_in[b][0][0]);
            dst[gt]       = src[gt];
            dst[gt + 256] = src[gt + 256];
        } else {
            const float* src = in_s + (size_t)cc * CHUNK * IN_DIM;
            for (int i = gt; i < CHUNK * IN_DIM; i += 256) {
                int t = i / IN_DIM;
                int k = i - t * IN_DIM;
                s_in[b][t][k] = src[i];
            }
        }
    };

    auto compute_xg = [&](int b) {
        const int gr = (wave - 1) * 64 + lane;
#pragma unroll 1
        for (int t = 0; t < CHUNK; ++t) {
            float a0 = bias, a1 = 0.0f, a2 = 0.0f, a3 = 0.0f;
#pragma unroll
            for (int k4 = 0; k4 < HID / 4; ++k4) {
                float4 u = *reinterpret_cast<const float4*>(&s_in[b][t][k4 * 4]);
                a0 = fmaf(wih[k4 * 4 + 0], u.x, a0);
                a1 = fmaf(wih[k4 * 4 + 1], u.y, a1);
                a2 = fmaf(wih[k4 * 4 + 2], u.z, a2);
                a3 = fmaf(wih[k4 * 4 + 3], u.w, a3);
            }
            s_xg[b][t][gr] = (a0 + a1) + (a2 + a3);
        }
    };

    // ---- prologue: prime s_xg[0] (chunk 0) and s_in[1] (chunk 1) ----
    if (wave != 0) stage(0, 0);
    __syncthreads();                                   // B2
    if (wave != 0) {
        compute_xg(0);
        stage(1, 1);
    }
    __syncthreads();                                   // B3

    // ---- main loop ----
    for (int ci = 0; ci < NCHUNK; ++ci) {
        const int buf = ci & 1;
        if (wave == 0) {
            // ---- 32 recurrence steps, zero barriers, all intra-wave ----
#pragma unroll 1
            for (int tt = 0; tt < CHUNK; ++tt) {
                float xg_i = s_xg[buf][tt][lane];
                float xg_f = s_xg[buf][tt][64 + lane];
                float xg_g = s_xg[buf][tt][128 + lane];
                float xg_o = s_xg[buf][tt][192 + lane];

                float ai0 = 0, ai1 = 0, ai2 = 0, ai3 = 0;
                float af0 = 0, af1 = 0, af2 = 0, af3 = 0;
                float ag0 = 0, ag1 = 0, ag2 = 0, ag3 = 0;
                float ao0 = 0, ao1 = 0, ao2 = 0, ao3 = 0;
#pragma unroll
                for (int k4 = 0; k4 < HID / 4; ++k4) {
                    float4 h4  = *reinterpret_cast<const float4*>(&s_hvec[k4 * 4]);     // broadcast
                    float4 wg4 = *reinterpret_cast<const float4*>(&s_wgo[0][k4][lane][0]);
                    float4 wo4 = *reinterpret_cast<const float4*>(&s_wgo[1][k4][lane][0]);
                    ai0 = fmaf(wi[k4 * 4 + 0], h4.x, ai0);
                    ai1 = fmaf(wi[k4 * 4 + 1], h4.y, ai1);
                    ai2 = fmaf(wi[k4 * 4 + 2], h4.z, ai2);
                    ai3 = fmaf(wi[k4 * 4 + 3], h4.w, ai3);
                    af0 = fmaf(wf[k4 * 4 + 0], h4.x, af0);
                    af1 = fmaf(wf[k4 * 4 + 1], h4.y, af1);
                    af2 = fmaf(wf[k4 * 4 + 2], h4.z, af2);
                    af3 = fmaf(wf[k4 * 4 + 3], h4.w, af3);
                    ag0 = fmaf(wg4.x, h4.x, ag0);
                    ag1 = fmaf(wg4.y, h4.y, ag1);
                    ag2 = fmaf(wg4.z, h4.z, ag2);
                    ag3 = fmaf(wg4.w, h4.w, ag3);
                    ao0 = fmaf(wo4.x, h4.x, ao0);
                    ao1 = fmaf(wo4.y, h4.y, ao1);
                    ao2 = fmaf(wo4.z, h4.z, ao2);
                    ao3 = fmaf(wo4.w, h4.w, ao3);
                }
                float pi = xg_i + ((ai0 + ai1) + (ai2 + ai3));
                float pf = xg_f + ((af0 + af1) + (af2 + af3));
                float pg = xg_g + ((ag0 + ag1) + (ag2 + ag3));
                float po = xg_o + ((ao0 + ao1) + (ao2 + ao3));

                float I = sigmoid_(pi);
                float F = sigmoid_(pf);
                float G = tanh_(pg);
                float O = sigmoid_(po);
                c = fmaf(F, c, I * G);
                h = O * tanh_(c);

                s_hvec[lane]    = h;   // next step's broadcast source (same wave)
                s_hout[tt][lane] = h;
            }
            // ---- coalesced chunk output (wave0 only; drains at the barrier)
            {
                const float4* src = reinterpret_cast<const float4*>(&s_hout[0][0]);
                float4* dst = reinterpret_cast<float4*>(out_s + (size_t)ci * CHUNK * HID);
#pragma unroll
                for (int r = 0; r < (CHUNK * HID) / (4 * 64); ++r)   // 8
                    dst[lane + 64 * r] = src[lane + 64 * r];
            }
        } else {
            if (ci + 2 < NCHUNK) stage(buf, ci + 2);       // input for chunk ci+2
            if (ci + 1 < NCHUNK) compute_xg(buf ^ 1);      // xg for chunk ci+1
        }
        __syncthreads();
    }
}

// MLP head: features = gelu(last @ Wl^T + bl); out = relu(features @ Wo^T + bo)
// d_out layout: out[256*4] first, then features[256*128].
__global__ __launch_bounds__(128)
void head_kernel(const float* __restrict__ h_buf,  // [B, T, HID]
                 const float* __restrict__ Wl,     // [128, 64]
                 const float* __restrict__ bl,     // [128]
                 const float* __restrict__ Wo,     // [4, 128]
                 const float* __restrict__ bo,     // [4]
                 float* __restrict__ d_out)
{
    __shared__ float s_last[HID];
    __shared__ float s_feat[128];
    const int s = blockIdx.x;
    const int j = threadIdx.x;

    if (j < HID)
        s_last[j] = h_buf[(size_t)s * T_SEQ * HID + (size_t)(T_SEQ - 1) * HID + j];
    __syncthreads();

    float acc = bl[j];
#pragma unroll
    for (int k = 0; k < HID; ++k)
        acc = fmaf(s_last[k], Wl[j * HID + k], acc);
    float f = 0.5f * acc * (1.0f + erff(acc * 0.70710678118654752440f));
    d_out[256 * 4 + s * 128 + j] = f;
    s_feat[j] = f;
    __syncthreads();

    if (j < 4) {
        float a = bo[j];
#pragma unroll
        for (int k = 0; k < 128; ++k)
            a = fmaf(s_feat[k], Wo[j * 128 + k], a);
        d_out[s * 4 + j] = fmaxf(a, 0.0f);
    }
}

extern "C" void kernel_launch(void* const* d_in, const int* in_sizes, int n_in,
                              void* d_out, int out_size, void* d_ws, size_t ws_size,
                              hipStream_t stream)
{
    const float* x         = (const float*)d_in[0];  // [256, 2048, 45]
    const float* W_ih0     = (const float*)d_in[1];  // [256, 45]
    const float* W_ih_rest = (const float*)d_in[2];  // [4, 256, 64]
    const float* W_hh      = (const float*)d_in[3];  // [5, 256, 64]
    const float* b_ih      = (const float*)d_in[4];  // [5, 256]
    const float* b_hh      = (const float*)d_in[5];  // [5, 256]
    const float* Wl        = (const float*)d_in[6];  // [128, 64]
    const float* bl        = (const float*)d_in[7];  // [128]
    const float* Wo        = (const float*)d_in[8];  // [4, 128]
    const float* bo        = (const float*)d_in[9];  // [4]

    float* h_buf = (float*)d_ws;  // [256, 2048, 64] fp32 = 134 MB

    lstm_layer_kernel<45><<<256, 320, 0, stream>>>(
        x, W_ih0, W_hh, b_ih, b_hh, h_buf);
    for (int l = 1; l < 5; ++l) {
        lstm_layer_kernel<64><<<256, 320, 0, stream>>>(
            h_buf,
            W_ih_rest + (size_t)(l - 1) * GATES * HID,
            W_hh + (size_t)l * GATES * HID,
            b_ih + (size_t)l * GATES,
            b_hh + (size_t)l * GATES,
            h_buf);
    }
    head_kernel<<<256, 128, 0, stream>>>(h_buf, Wl, bl, Wo, bo, (float*)d_out);
}

// Round 4
// 10236.436 us; speedup vs baseline: 3.1889x; 3.1889x over previous
//
#include <hip/hip_runtime.h>
#include <math.h>

#define T_SEQ 2048
#define HID   64
#define GATES 256
#define CHUNK 32
#define NCHUNK (T_SEQ / CHUNK)   // 64

typedef __attribute__((ext_vector_type(2))) float f32x2;
typedef __attribute__((ext_vector_type(4))) float f32x4;

__device__ __forceinline__ float sigmoid_(float x) {
    return 1.0f / (1.0f + __expf(-x));
}
__device__ __forceinline__ float tanh_(float x) {
    float e = __expf(2.0f * x);
    return 1.0f - 2.0f / (e + 1.0f);
}

// One LSTM layer over the whole sequence.
// grid = 256 blocks (1 per sample), block = 256 threads (4 waves, 1 per EU so
// each wave can use up to 512 VGPRs -- round 3 failed because a 5-wave block
// capped VGPRs at 128 and spilled the weight arrays to scratch):
//   wave 0   : entire recurrence, barrier-free. lane j owns hidden unit j and
//              ALL FOUR gate rows (j, 64+j, 128+j, 192+j), weights in VGPRs
//              (256 regs as 128 x f32x2 -> v_pk_fma_f32). Per-step LDS traffic:
//              16 uniform-broadcast b128 reads of h + 4 xg reads + 1 h write.
//              h goes straight to global (fire-and-forget, drains per chunk).
//   waves 1-3: input GEMM for chunk ci+1 (xg = in @ W_ih^T + b), double
//              buffered; input rows staged 2 chunks ahead. wave1 handles two
//              gate rows (192 threads, 256 rows) -- wave-uniform split.
// One barrier per CHUNK steps. in/out may alias (in-place): chunk c is read at
// iteration c-2 and written at iteration c.
template <int IN_DIM>
__global__ __launch_bounds__(256, 1)
void lstm_layer_kernel(const float* in,
                       const float* __restrict__ W_ih,   // [GATES, IN_DIM]
                       const float* __restrict__ W_hh,   // [GATES, HID]
                       const float* __restrict__ b_ih,   // [GATES]
                       const float* __restrict__ b_hh,   // [GATES]
                       float* out)
{
    __shared__ float s_xg[2][CHUNK][GATES];        // 64 KB  xg double buffer
    __shared__ float s_in[2][CHUNK][HID];          // 16 KB  staged input rows
    __shared__ float s_hvec[HID];                  // 256 B  current h (broadcast)

    const int tid  = threadIdx.x;
    const int wave = tid >> 6;       // 0..3
    const int lane = tid & 63;
    const int s    = blockIdx.x;

    const float* in_s  = in  + (size_t)s * T_SEQ * IN_DIM;
    float*       out_s = out + (size_t)s * T_SEQ * HID;

    // ---- zero s_in (padding cols for IN_DIM<64 stay 0 forever) + h0
    for (int i = tid; i < 2 * CHUNK * HID; i += 256) ((float*)s_in)[i] = 0.0f;
    if (tid < HID) s_hvec[tid] = 0.0f;
    __syncthreads();                                   // B1

    // ---- per-wave setup ----
    f32x2 wi[32], wf[32], wg[32], wo[32];  // wave0: all 4 gate rows (256 VGPR)
    float wih0[HID], wih1[HID];            // waves 1-3: W_ih rows
    float bias0 = 0.0f, bias1 = 0.0f;
    float c = 0.0f, h = 0.0f;

    if (wave == 0) {
#pragma unroll
        for (int k2 = 0; k2 < 32; ++k2) {
            wi[k2] = *reinterpret_cast<const f32x2*>(&W_hh[(size_t)(lane)       * HID + 2 * k2]);
            wf[k2] = *reinterpret_cast<const f32x2*>(&W_hh[(size_t)(64  + lane) * HID + 2 * k2]);
            wg[k2] = *reinterpret_cast<const f32x2*>(&W_hh[(size_t)(128 + lane) * HID + 2 * k2]);
            wo[k2] = *reinterpret_cast<const f32x2*>(&W_hh[(size_t)(192 + lane) * HID + 2 * k2]);
        }
    } else {
        const int gt = tid - 64;             // 0..191
        const int r0 = gt;                   // first gate row
        const int r1 = 192 + gt;             // second row (only wave1: gt<64)
#pragma unroll
        for (int k = 0; k < HID; ++k)
            wih0[k] = (k < IN_DIM) ? W_ih[(size_t)r0 * IN_DIM + k] : 0.0f;
        bias0 = b_ih[r0] + b_hh[r0];
        if (gt < 64) {
#pragma unroll
            for (int k = 0; k < HID; ++k)
                wih1[k] = (k < IN_DIM) ? W_ih[(size_t)r1 * IN_DIM + k] : 0.0f;
            bias1 = b_ih[r1] + b_hh[r1];
        }
    }

    // ---- GEMM-side helpers ----
    const int gt = tid - 64;  // 0..191 for waves 1-3

    auto stage = [&](int b, int cc) {
        const float* src = in_s + (size_t)cc * CHUNK * IN_DIM;
        if (IN_DIM == 64) {
            const float4* s4 = reinterpret_cast<const float4*>(src);
            float4* dst = reinterpret_cast<float4*>(&s_in[b][0][0]);
            // 512 float4 elems, 192 threads
            dst[gt]       = s4[gt];
            dst[gt + 192] = s4[gt + 192];
            if (gt < 128) dst[gt + 384] = s4[gt + 384];
        } else {
            for (int i = gt; i < CHUNK * IN_DIM; i += 192) {
                int t = i / IN_DIM;
                int k = i - t * IN_DIM;
                s_in[b][t][k] = src[i];
            }
        }
    };

    auto compute_xg = [&](int b) {
#pragma unroll 1
        for (int t = 0; t < CHUNK; ++t) {
            float a0 = bias0, a1 = 0.0f, a2 = 0.0f, a3 = 0.0f;
#pragma unroll
            for (int k4 = 0; k4 < HID / 4; ++k4) {
                float4 u = *reinterpret_cast<const float4*>(&s_in[b][t][k4 * 4]);
                a0 = fmaf(wih0[k4 * 4 + 0], u.x, a0);
                a1 = fmaf(wih0[k4 * 4 + 1], u.y, a1);
                a2 = fmaf(wih0[k4 * 4 + 2], u.z, a2);
                a3 = fmaf(wih0[k4 * 4 + 3], u.w, a3);
            }
            s_xg[b][t][gt] = (a0 + a1) + (a2 + a3);
            if (gt < 64) {   // wave1 entirely: second row, no divergence
                float c0 = bias1, c1 = 0.0f, c2 = 0.0f, c3 = 0.0f;
#pragma unroll
                for (int k4 = 0; k4 < HID / 4; ++k4) {
                    float4 u = *reinterpret_cast<const float4*>(&s_in[b][t][k4 * 4]);
                    c0 = fmaf(wih1[k4 * 4 + 0], u.x, c0);
                    c1 = fmaf(wih1[k4 * 4 + 1], u.y, c1);
                    c2 = fmaf(wih1[k4 * 4 + 2], u.z, c2);
                    c3 = fmaf(wih1[k4 * 4 + 3], u.w, c3);
                }
                s_xg[b][t][192 + gt] = (c0 + c1) + (c2 + c3);
            }
        }
    };

    // ---- prologue: prime s_xg[0] (chunk 0) and s_in[1] (chunk 1) ----
    if (wave != 0) stage(0, 0);
    __syncthreads();                                   // B2
    if (wave != 0) {
        compute_xg(0);
        stage(1, 1);
    }
    __syncthreads();                                   // B3

    // ---- main loop ----
    for (int ci = 0; ci < NCHUNK; ++ci) {
        const int buf = ci & 1;
        if (wave == 0) {
            // ---- 32 recurrence steps, zero barriers, all intra-wave ----
#pragma unroll 1
            for (int tt = 0; tt < CHUNK; ++tt) {
                // xg reads: independent of h chain, issue first
                float xg_i = s_xg[buf][tt][lane];
                float xg_f = s_xg[buf][tt][64 + lane];
                float xg_g = s_xg[buf][tt][128 + lane];
                float xg_o = s_xg[buf][tt][192 + lane];

                f32x2 ai0 = {0, 0}, ai1 = {0, 0};
                f32x2 af0 = {0, 0}, af1 = {0, 0};
                f32x2 ag0 = {0, 0}, ag1 = {0, 0};
                f32x2 ao0 = {0, 0}, ao1 = {0, 0};
#pragma unroll
                for (int k4 = 0; k4 < HID / 4; ++k4) {
                    f32x4 hv = *reinterpret_cast<const f32x4*>(&s_hvec[k4 * 4]);  // broadcast
                    f32x2 h01 = hv.xy;
                    f32x2 h23 = hv.zw;
                    ai0 = wi[2 * k4] * h01 + ai0;        // v_pk_fma_f32
                    ai1 = wi[2 * k4 + 1] * h23 + ai1;
                    af0 = wf[2 * k4] * h01 + af0;
                    af1 = wf[2 * k4 + 1] * h23 + af1;
                    ag0 = wg[2 * k4] * h01 + ag0;
                    ag1 = wg[2 * k4 + 1] * h23 + ag1;
                    ao0 = wo[2 * k4] * h01 + ao0;
                    ao1 = wo[2 * k4 + 1] * h23 + ao1;
                }
                f32x2 si = ai0 + ai1;
                f32x2 sf = af0 + af1;
                f32x2 sg = ag0 + ag1;
                f32x2 so = ao0 + ao1;
                float pi = xg_i + (si.x + si.y);
                float pf = xg_f + (sf.x + sf.y);
                float pg = xg_g + (sg.x + sg.y);
                float po = xg_o + (so.x + so.y);

                float I = sigmoid_(pi);
                float F = sigmoid_(pf);
                float G = tanh_(pg);
                float O = sigmoid_(po);
                c = fmaf(F, c, I * G);
                h = O * tanh_(c);

                s_hvec[lane] = h;                              // next-step broadcast
                out_s[(size_t)(ci * CHUNK + tt) * HID + lane] = h;  // fire-and-forget
            }
        } else {
            if (ci + 2 < NCHUNK) stage(buf, ci + 2);       // input for chunk ci+2
            if (ci + 1 < NCHUNK) compute_xg(buf ^ 1);      // xg for chunk ci+1
        }
        __syncthreads();
    }
}

// MLP head: features = gelu(last @ Wl^T + bl); out = relu(features @ Wo^T + bo)
// d_out layout: out[256*4] first, then features[256*128].
__global__ __launch_bounds__(128)
void head_kernel(const float* __restrict__ h_buf,  // [B, T, HID]
                 const float* __restrict__ Wl,     // [128, 64]
                 const float* __restrict__ bl,     // [128]
                 const float* __restrict__ Wo,     // [4, 128]
                 const float* __restrict__ bo,     // [4]
                 float* __restrict__ d_out)
{
    __shared__ float s_last[HID];
    __shared__ float s_feat[128];
    const int s = blockIdx.x;
    const int j = threadIdx.x;

    if (j < HID)
        s_last[j] = h_buf[(size_t)s * T_SEQ * HID + (size_t)(T_SEQ - 1) * HID + j];
    __syncthreads();

    float acc = bl[j];
#pragma unroll
    for (int k = 0; k < HID; ++k)
        acc = fmaf(s_last[k], Wl[j * HID + k], acc);
    float f = 0.5f * acc * (1.0f + erff(acc * 0.70710678118654752440f));
    d_out[256 * 4 + s * 128 + j] = f;
    s_feat[j] = f;
    __syncthreads();

    if (j < 4) {
        float a = bo[j];
#pragma unroll
        for (int k = 0; k < 128; ++k)
            a = fmaf(s_feat[k], Wo[j * 128 + k], a);
        d_out[s * 4 + j] = fmaxf(a, 0.0f);
    }
}

extern "C" void kernel_launch(void* const* d_in, const int* in_sizes, int n_in,
                              void* d_out, int out_size, void* d_ws, size_t ws_size,
                              hipStream_t stream)
{
    const float* x         = (const float*)d_in[0];  // [256, 2048, 45]
    const float* W_ih0     = (const float*)d_in[1];  // [256, 45]
    const float* W_ih_rest = (const float*)d_in[2];  // [4, 256, 64]
    const float* W_hh      = (const float*)d_in[3];  // [5, 256, 64]
    const float* b_ih      = (const float*)d_in[4];  // [5, 256]
    const float* b_hh      = (const float*)d_in[5];  // [5, 256]
    const float* Wl        = (const float*)d_in[6];  // [128, 64]
    const float* bl        = (const float*)d_in[7];  // [128]
    const float* Wo        = (const float*)d_in[8];  // [4, 128]
    const float* bo        = (const float*)d_in[9];  // [4]

    float* h_buf = (float*)d_ws;  // [256, 2048, 64] fp32 = 134 MB

    lstm_layer_kernel<45><<<256, 256, 0, stream>>>(
        x, W_ih0, W_hh, b_ih, b_hh, h_buf);
    for (int l = 1; l < 5; ++l) {
        lstm_layer_kernel<64><<<256, 256, 0, stream>>>(
            h_buf,
            W_ih_rest + (size_t)(l - 1) * GATES * HID,
            W_hh + (size_t)l * GATES * HID,
            b_ih + (size_t)l * GATES,
            b_hh + (size_t)l * GATES,
            h_buf);
    }
    head_kernel<<<256, 128, 0, stream>>>(h_buf, Wl, bl, Wo, bo, (float*)d_out);
}